// Round 20
// baseline (186.981 us; speedup 1.0000x reference)
//
#include <hip/hip_runtime.h>
#include <hip/hip_bf16.h>

typedef __attribute__((ext_vector_type(8))) short short8;
typedef __attribute__((ext_vector_type(4))) float f32x4;
typedef __attribute__((ext_vector_type(4))) int int4v;
typedef __attribute__((ext_vector_type(8))) char char8v;
typedef __attribute__((ext_vector_type(4), aligned(4))) unsigned int uint4a;

static constexpr int B = 64, N = 198, C = 768, H = 12, D = 64;
static constexpr int M = B * N;          // 12672 = 198*64
static constexpr int BH = B * H;         // 768
static constexpr int O3C = 3 * C;        // 2304
static constexpr int KC = 48;            // k-chunks of 16B over K=768
static constexpr int NXT = 198;          // 64-row x-tiles
static constexpr int NXTP = 200;         // padded to 25*8 for XCD affinity
static constexpr int AL8 = 272;          // attn P-stripe i8 stride
static constexpr int VNP = 256;          // V^T i8 padded cols
static constexpr int TLQ = 272;          // gemm1 Q/K bounce tile stride
static constexpr int TLV = 80;           // gemm1 V bounce tile stride (transposed)

// Tiled i8 layout: T(mt,kc,r16,b) = ((mt*KC + kc)*16 + r16)*16 + b
// Fragment load for (mt, kstep t): addr = (mt*KC)*256 + t*1024 + lane*16 (1KB coalesced)

// ---- workspace layout (bytes) ----
static constexpr size_t OFF_MEANS = 0;
static constexpr size_t OFF_TAB   = 256;
static constexpr size_t OFF_PARTA = 2048;    // 2048 doubles = 16384 B
static constexpr size_t OFF_PARTP = 18432;   // 2048 doubles
static constexpr size_t OFF_XS    = 36864;
static constexpr size_t SZ_XS     = (size_t)M * C;           // tiled sign(x)
static constexpr size_t OFF_WQS   = OFF_XS + SZ_XS;
static constexpr size_t SZ_WQS    = (size_t)O3C * C;         // tiled sign(qkv_w)
static constexpr size_t OFF_WPS   = OFF_WQS + SZ_WQS;
static constexpr size_t SZ_WPS    = (size_t)C * C;           // tiled sign(proj_w)
static constexpr size_t OFF_Q     = OFF_WPS + SZ_WPS;
static constexpr size_t SZ_QK8    = (size_t)BH * N * D;
static constexpr size_t OFF_K     = OFF_Q + SZ_QK8;
static constexpr size_t OFF_VT    = OFF_K + SZ_QK8;
static constexpr size_t SZ_VT8    = (size_t)BH * D * VNP;
static constexpr size_t OFF_OS    = OFF_VT + SZ_VT8;         // tiled attn-out signs

__global__ void finalize_kernel(const double* __restrict__ pA, const double* __restrict__ pP,
                                double* __restrict__ means, double* __restrict__ tab,
                                const float* cq, const float* ck) {
  __shared__ double sm[256];
  int t = threadIdx.x;
  double s = 0.0;
  for (int j = t; j < 2048; j += 256) s += pA[j];
  sm[t] = s;
  __syncthreads();
  for (int off = 128; off > 0; off >>= 1) { if (t < off) sm[t] += sm[t + off]; __syncthreads(); }
  if (t == 0) means[0] = sm[0] / (double)((size_t)O3C * C);
  __syncthreads();
  s = 0.0;
  for (int j = t; j < 2048; j += 256) s += pP[j];
  sm[t] = s;
  __syncthreads();
  for (int off = 128; off > 0; off >>= 1) { if (t < off) sm[t] += sm[t + off]; __syncthreads(); }
  if (t == 0) means[1] = sm[0] / (double)((size_t)C * C);
  double delta = (double)cq[0] * (double)ck[0] * 0.125;
  if (t < 129) tab[t] = exp((double)(t - 128) * delta);
  if (t < 16) tab[129 + t] = exp((double)t * delta);
}

// ---------- sign -> TILED i8 layout, FUSED |w| partial reduction ----------
// unit u = (row, kc): reads 64B coalesced, writes 16B to tiled layout.
__global__ void sign8_tiled_kernel(const float* __restrict__ x, signed char* __restrict__ Xs,
                                   const float* __restrict__ qw, signed char* __restrict__ Wq,
                                   const float* __restrict__ pw, signed char* __restrict__ Wp,
                                   int ux, int uq, int up, const float* alpha,
                                   double* __restrict__ partA, double* __restrict__ partP) {
  __shared__ double sm[256];
  float a = alpha[0];
  signed char posx = (a > 0.0f) ? 1 : ((a < 0.0f) ? -1 : 0);
  int total = ux + uq + up;
  int stride = 256 * gridDim.x;
  double sq = 0.0, sp = 0.0;
  for (int u = blockIdx.x * 256 + threadIdx.x; u < total; u += stride) {
    const float* src;
    signed char* dst;
    int j;
    signed char pos;
    int which;
    if (u < ux) { src = x; dst = Xs; j = u; pos = posx; which = 0; }
    else if (u < ux + uq) { src = qw; dst = Wq; j = u - ux; pos = 1; which = 1; }
    else { src = pw; dst = Wp; j = u - ux - uq; pos = 1; which = 2; }
    signed char neg = (signed char)(-pos);
    int row = j / KC, kc = j - row * KC;
    const float4* xp = (const float4*)(src + (size_t)row * C + kc * 16);
    signed char out16[16];
    double asum = 0.0;
#pragma unroll
    for (int q4 = 0; q4 < 4; ++q4) {
      float4 v = xp[q4];
      float vv[4] = {v.x, v.y, v.z, v.w};
#pragma unroll
      for (int k = 0; k < 4; ++k) {
        out16[q4 * 4 + k] = vv[k] > 0.0f ? pos : (vv[k] < 0.0f ? neg : (signed char)0);
        asum += (double)fabsf(vv[k]);
      }
    }
    if (which == 1) sq += asum;
    else if (which == 2) sp += asum;
    size_t off = (((size_t)(row >> 4) * KC + kc) * 16 + (row & 15)) * 16;
    *(uint4a*)(dst + off) = *(const uint4a*)out16;
  }
  sm[threadIdx.x] = sq;
  __syncthreads();
  for (int off = 128; off > 0; off >>= 1) {
    if (threadIdx.x < (unsigned)off) sm[threadIdx.x] += sm[threadIdx.x + off];
    __syncthreads();
  }
  if (threadIdx.x == 0) partA[blockIdx.x] = sm[0];
  __syncthreads();
  sm[threadIdx.x] = sp;
  __syncthreads();
  for (int off = 128; off > 0; off >>= 1) {
    if (threadIdx.x < (unsigned)off) sm[threadIdx.x] += sm[threadIdx.x + off];
    __syncthreads();
  }
  if (threadIdx.x == 0) partP[blockIdx.x] = sm[0];
}

// XCD-affinity decode (limit-parameterized)
static __device__ inline bool xcd_decode(int lin, int nyb, int limit, int& x, int& y) {
  int k = lin & 7;
  int q = lin >> 3;
  int xi = q / nyb;
  y = q - xi * nyb;
  x = xi * 8 + k;
  return x < limit;
}

// ---------- barrier-free tiled-fragment i8 GEMM, MANUAL register double-buffer ----------
// Loads for step t+1 are issued BEFORE the MFMAs of step t (ping-pong a0/b0 vs a1/b1,
// all indices compile-time). Each 1KB coalesced load has a full MFMA phase in flight
// before its waitcnt -> L2 latency hidden.
static __device__ inline void gemm_reg_i8(const signed char* __restrict__ At,
                                          const signed char* __restrict__ Bt,
                                          int x4, int nt0, int4v acc[4][4]) {
  int lane = threadIdx.x & 63;
  const signed char* ap = At + ((size_t)x4 * KC) * 256 + lane * 16;
  const signed char* bp = Bt + ((size_t)nt0 * KC) * 256 + lane * 16;
  int4v a0[4], b0[4], a1[4], b1[4];
#pragma unroll
  for (int m = 0; m < 4; ++m) a0[m] = *(const int4v*)(ap + (size_t)m * KC * 256);
#pragma unroll
  for (int n = 0; n < 4; ++n) b0[n] = *(const int4v*)(bp + (size_t)n * KC * 256);
#pragma unroll
  for (int t = 0; t < 12; t += 2) {
#pragma unroll
    for (int m = 0; m < 4; ++m) a1[m] = *(const int4v*)(ap + (size_t)m * KC * 256 + (t + 1) * 1024);
#pragma unroll
    for (int n = 0; n < 4; ++n) b1[n] = *(const int4v*)(bp + (size_t)n * KC * 256 + (t + 1) * 1024);
#pragma unroll
    for (int m = 0; m < 4; ++m)
#pragma unroll
      for (int n = 0; n < 4; ++n)
        acc[m][n] = __builtin_amdgcn_mfma_i32_16x16x64_i8(a0[m], b0[n], acc[m][n], 0, 0, 0);
    if (t + 2 < 12) {
#pragma unroll
      for (int m = 0; m < 4; ++m) a0[m] = *(const int4v*)(ap + (size_t)m * KC * 256 + (t + 2) * 1024);
#pragma unroll
      for (int n = 0; n < 4; ++n) b0[n] = *(const int4v*)(bp + (size_t)n * KC * 256 + (t + 2) * 1024);
    }
#pragma unroll
    for (int m = 0; m < 4; ++m)
#pragma unroll
      for (int n = 0; n < 4; ++n)
        acc[m][n] = __builtin_amdgcn_mfma_i32_16x16x64_i8(a1[m], b1[n], acc[m][n], 0, 0, 0);
  }
}

// ---------- GEMM1: 64 rows x 256 cols per block; grid 200 x 9 panels ----------
__global__ __launch_bounds__(256) void gemm1_kernel(
    const signed char* __restrict__ Xs, const signed char* __restrict__ Wqs,
    const double* __restrict__ means,
    const float* cin, const float* cq, const float* ck,
    const float* cv1, const float* cv2, const float* cv3,
    const float* __restrict__ movq, const float* __restrict__ movk, const float* __restrict__ movv,
    signed char* __restrict__ Qs8, signed char* __restrict__ Ks8, signed char* __restrict__ Vt8) {
  int bx, by;
  if (!xcd_decode(blockIdx.x, 9, NXT, bx, by)) return;
  __shared__ __align__(16) signed char tile8[20480];   // Q/K [64][TLQ] or V [256][TLV]
  int tid = threadIdx.x;
  int lane = tid & 63, w = tid >> 6;
  int4v acc[4][4] = {};
  gemm_reg_i8(Xs, Wqs, bx * 4, by * 16 + w * 4, acc);
  double cw_ = (double)cin[0] * means[0];
  float dq = cq[0], dk = ck[0];
  signed char sq8 = dq > 0.0f ? 1 : (dq < 0.0f ? -1 : 0);
  signed char sk8 = dk > 0.0f ? 1 : (dk < 0.0f ? -1 : 0);
  double aa1 = fabs((double)cv1[0]), aa2 = fabs((double)cv2[0]), aa3 = fabs((double)cv3[0]);
  int t = by / 3;                       // 0=Q,1=K,2=V
  int rem0 = (by - t * 3) * 256;
  signed char sg8 = t == 0 ? sq8 : sk8;
  const float* mov = t == 0 ? movq : (t == 1 ? movk : movv);
  int g = lane >> 4, q16 = lane & 15;
#pragma unroll
  for (int m = 0; m < 4; ++m)
#pragma unroll
    for (int n2 = 0; n2 < 4; ++n2)
#pragma unroll
      for (int r = 0; r < 4; ++r) {
        int rowL = m * 16 + g * 4 + r;          // 0..63
        int colL = w * 64 + n2 * 16 + q16;      // 0..255
        int rem = rem0 + colL;
        int h = rem >> 6, d = rem & 63;
        double gg = (double)acc[m][n2][r] * cw_;
        if (t < 2) {
          double v = gg + (double)mov[h * D + d];
          tile8[rowL * TLQ + colL] = v > 0.0 ? sg8 : (v < 0.0 ? (signed char)(-sg8) : (signed char)0);
        } else {
          double rr = gg + (double)mov[h * D + d];
          double b1 = rr > 0.0 ? aa1 : (rr < 0.0 ? -aa1 : 0.0);
          rr -= b1;
          double b2 = rr > 0.0 ? aa2 : (rr < 0.0 ? -aa2 : 0.0);
          rr -= b2;
          double b3 = rr > 0.0 ? aa3 : (rr < 0.0 ? -aa3 : 0.0);
          tile8[colL * TLV + rowL] = (signed char)(int)rint(4.0 * (b1 + b2 + b3)); // transposed
        }
      }
  __syncthreads();
  if (t < 2) {
    signed char* dst = t == 0 ? Qs8 : Ks8;
#pragma unroll
    for (int it = 0; it < 4; ++it) {
      int c = tid + it * 256;            // 1024 chunks of 16B (64 rows x 16 col-chunks)
      int rowL = c >> 4, cch = c & 15;
      int gr = bx * 64 + rowL;
      int b = gr / N, nn = gr - b * N;
      int rem = rem0 + cch * 16;
      int h = rem >> 6, d = rem & 63;
      *(uint4a*)&dst[((size_t)(b * H + h) * N + nn) * 64 + d] =
          *(const uint4a*)&tile8[rowL * TLQ + cch * 16];
    }
  } else {
#pragma unroll
    for (int it = 0; it < 4; ++it) {
      int c = tid + it * 256;            // 1024 chunks: 256 cols x 4 row-chunks of 16
      int colL = c >> 2, tch = c & 3;
      int rem = rem0 + colL;
      int h = rem >> 6, d = rem & 63;
      int gr0 = bx * 64 + tch * 16;
      int b0 = gr0 / N, nn0 = gr0 - b0 * N;
      if (nn0 + 16 <= N) {
        *(uint4a*)&Vt8[((size_t)(b0 * H + h) * 64 + d) * VNP + nn0] =
            *(const uint4a*)&tile8[colL * TLV + tch * 16];
      } else {
#pragma unroll
        for (int j = 0; j < 16; ++j) {
          int gr = gr0 + j;
          int b = gr / N, nn = gr - b * N;
          Vt8[((size_t)(b * H + h) * 64 + d) * VNP + nn] = tile8[colL * TLV + tch * 16 + j];
        }
      }
    }
  }
}

// ---------- fused attention v7: all-i8, 4 waves/block, XCD-affine, tiled Os out ----------
__global__ __launch_bounds__(256) void attn_kernel(
    const signed char* __restrict__ Qs8, const signed char* __restrict__ Ks8,
    const signed char* __restrict__ Vt8, const double* __restrict__ tab,
    const float* __restrict__ movatt,
    const float* ca1p, const float* ca2p, const float* ca3p, const float* cipp,
    signed char* __restrict__ Os) {
  __shared__ double Tl1[9];
  __shared__ double Tl2[16];
  __shared__ signed char Al8[4][16 * AL8];
  int i = blockIdx.x;
  int xcd = i & 7;
  int q = i >> 3;
  int rt = q % 13;
  int grp = q / 13;
  int tid = threadIdx.x;
  int w = tid >> 6, lane = tid & 63;
  int bh = (grp * 4 + w) * 8 + xcd;
  int b = bh / H, h = bh - b * H;
  int g = lane >> 4, q16 = lane & 15;
  if (tid < 9) Tl1[tid] = tab[16 * tid];
  if (tid >= 32 && tid < 48) Tl2[tid - 32] = tab[129 + (tid - 32)];
  for (int ii = lane; ii < 192; ii += 64) {
    int row = ii / 12, cd = ii - row * 12;
    *(int*)&Al8[w][row * AL8 + 208 + cd * 4] = 0;
  }
  __syncthreads();
  double ca1 = (double)ca1p[0], ca2 = (double)ca2p[0], ca3 = (double)ca3p[0];
  double t1 = 0.5 * ca1, t2 = 0.5 * ca2, t3 = 0.5 * ca3;
  int q1 = (int)rint(4.0 * ca1), q2 = (int)rint(4.0 * ca2), q3 = (int)rint(4.0 * ca3);
  float cip = cipp[0];
  signed char cp = cip > 0.0f ? 1 : (cip < 0.0f ? -1 : 0);

  int4v qf = {};
  int qrow = rt * 16 + q16;
  if (qrow < N) qf = *(const int4v*)&Qs8[((size_t)bh * N + qrow) * 64 + g * 16];
  int4v sacc[13] = {};
#pragma unroll
  for (int ct = 0; ct < 13; ++ct) {
    int krow = ct * 16 + q16;
    int4v kf = {};
    if (krow < N) kf = *(const int4v*)&Ks8[((size_t)bh * N + krow) * 64 + g * 16];
    sacc[ct] = __builtin_amdgcn_mfma_i32_16x16x64_i8(qf, kf, sacc[ct], 0, 0, 0);
  }
#pragma unroll
  for (int r = 0; r < 4; ++r) {
    int rowg = rt * 16 + g * 4 + r;
    int rowc = rowg < N ? rowg : N - 1;
    const float* mrow = movatt + ((size_t)h * N + rowc) * N;
    int mx = -1000000;
#pragma unroll
    for (int ct = 0; ct < 13; ++ct) {
      int colc = ct * 16 + q16;
      if (colc < N) mx = max(mx, sacc[ct][r]);
    }
    mx = max(mx, __shfl_xor(mx, 1));
    mx = max(mx, __shfl_xor(mx, 2));
    mx = max(mx, __shfl_xor(mx, 4));
    mx = max(mx, __shfl_xor(mx, 8));
    double ev[13];
    double ssum = 0.0;
#pragma unroll
    for (int ct = 0; ct < 13; ++ct) {
      int colc = ct * 16 + q16;
      int idx = sacc[ct][r] - mx + 128;
      idx = idx > 128 ? 128 : idx;
      double e = (colc < N) ? Tl1[idx >> 4] * Tl2[idx & 15] : 0.0;
      ev[ct] = e;
      ssum += e;
    }
    ssum += __shfl_xor(ssum, 1);
    ssum += __shfl_xor(ssum, 2);
    ssum += __shfl_xor(ssum, 4);
    ssum += __shfl_xor(ssum, 8);
    double rec = 1.0 / ssum;
#pragma unroll
    for (int ct = 0; ct < 13; ++ct) {
      int colc = ct * 16 + q16;
      int colb = colc < N ? colc : N - 1;
      double at = ev[ct] * rec + (double)mrow[colb];
      int p4 = 0;
      double rr = at;
      if (rr > t1) { p4 += q1; rr -= ca1; }
      if (rr > t2) { p4 += q2; rr -= ca2; }
      if (rr > t3) { p4 += q3; }
      Al8[w][(g * 4 + r) * AL8 + colc] = (signed char)((colc < N) ? p4 : 0);
    }
  }
  int4v oacc[4] = {};
#pragma unroll
  for (int kt = 0; kt < 4; ++kt) {
    int4v af = *(const int4v*)&Al8[w][q16 * AL8 + kt * 64 + g * 16];
#pragma unroll
    for (int dt = 0; dt < 4; ++dt) {
      int4v bv = *(const int4v*)&Vt8[((size_t)bh * 64 + dt * 16 + q16) * VNP + kt * 64 + g * 16];
      oacc[dt] = __builtin_amdgcn_mfma_i32_16x16x64_i8(af, bv, oacc[dt], 0, 0, 0);
    }
  }
  // tiled Os write
#pragma unroll
  for (int dt = 0; dt < 4; ++dt)
#pragma unroll
    for (int r = 0; r < 4; ++r) {
      int rowg = rt * 16 + g * 4 + r;
      if (rowg < N) {
        size_t grow = (size_t)b * N + rowg;
        int s = oacc[dt][r];
        Os[(grow >> 4) * (KC * 256) + (size_t)(h * 4 + dt) * 256 + (grow & 15) * 16 + q16] =
            s > 0 ? cp : (s < 0 ? (signed char)(-cp) : (signed char)0);
      }
    }
}

// ---------- GEMM2: 64 rows x 256 cols; grid 200 x 3 panels; f32 out ----------
__global__ __launch_bounds__(256) void gemm2_kernel(
    const signed char* __restrict__ Ot, const signed char* __restrict__ Wps,
    const double* __restrict__ means, const float* cip, const float* __restrict__ proj_b,
    float* __restrict__ out) {
  int bx, by;
  if (!xcd_decode(blockIdx.x, 3, NXT, bx, by)) return;
  int tid = threadIdx.x;
  int lane = tid & 63, w = tid >> 6;
  int4v acc[4][4] = {};
  gemm_reg_i8(Ot, Wps, bx * 4, by * 16 + w * 4, acc);
  double cw_ = (double)cip[0] * means[1];
  int g = lane >> 4, q16 = lane & 15;
#pragma unroll
  for (int m = 0; m < 4; ++m)
#pragma unroll
    for (int n2 = 0; n2 < 4; ++n2)
#pragma unroll
      for (int r = 0; r < 4; ++r) {
        int row = bx * 64 + m * 16 + g * 4 + r;
        int col = by * 256 + w * 64 + n2 * 16 + q16;
        double v = (double)acc[m][n2][r] * cw_ + (double)proj_b[col];
        out[(size_t)row * C + col] = (float)v;
      }
}

extern "C" void kernel_launch(void* const* d_in, const int* in_sizes, int n_in,
                              void* d_out, int out_size, void* d_ws, size_t ws_size,
                              hipStream_t stream) {
  const float* x      = (const float*)d_in[0];
  const float* qkv_w  = (const float*)d_in[1];
  const float* proj_w = (const float*)d_in[2];
  const float* proj_b = (const float*)d_in[3];
  const float* movq   = (const float*)d_in[4];
  const float* movk   = (const float*)d_in[5];
  const float* movv   = (const float*)d_in[6];
  const float* movatt = (const float*)d_in[7];
  const float* c_inq  = (const float*)d_in[8];
  const float* c_q    = (const float*)d_in[9];
  const float* c_k    = (const float*)d_in[10];
  const float* c_v1   = (const float*)d_in[11];
  const float* c_v2   = (const float*)d_in[12];
  const float* c_v3   = (const float*)d_in[13];
  const float* c_a1   = (const float*)d_in[14];
  const float* c_a2   = (const float*)d_in[15];
  const float* c_a3   = (const float*)d_in[16];
  const float* c_inp  = (const float*)d_in[17];

  char* ws = (char*)d_ws;
  double* means = (double*)(ws + OFF_MEANS);
  double* tab   = (double*)(ws + OFF_TAB);
  double* partA = (double*)(ws + OFF_PARTA);
  double* partP = (double*)(ws + OFF_PARTP);
  signed char* Xs  = (signed char*)(ws + OFF_XS);
  signed char* Wqs = (signed char*)(ws + OFF_WQS);
  signed char* Wps = (signed char*)(ws + OFF_WPS);
  signed char* Qs8 = (signed char*)(ws + OFF_Q);
  signed char* Ks8 = (signed char*)(ws + OFF_K);
  signed char* Vt8 = (signed char*)(ws + OFF_VT);
  signed char* Os  = (signed char*)(ws + OFF_OS);

  sign8_tiled_kernel<<<2048, 256, 0, stream>>>(x, Xs, qkv_w, Wqs, proj_w, Wps,
                                               M * KC, O3C * KC, C * KC, c_inq,
                                               partA, partP);
  finalize_kernel<<<1, 256, 0, stream>>>(partA, partP, means, tab, c_q, c_k);
  gemm1_kernel<<<NXTP * 9, 256, 0, stream>>>(
      Xs, Wqs, means, c_inq, c_q, c_k, c_v1, c_v2, c_v3, movq, movk, movv, Qs8, Ks8, Vt8);
  attn_kernel<<<8 * 13 * (BH / 32), 256, 0, stream>>>(Qs8, Ks8, Vt8, tab, movatt, c_a1, c_a2, c_a3, c_inp, Os);
  gemm2_kernel<<<NXTP * 3, 256, 0, stream>>>(
      Os, Wps, means, c_inp, proj_b, (float*)d_out);
}

// Round 21
// 155.929 us; speedup vs baseline: 1.1991x; 1.1991x over previous
//
#include <hip/hip_runtime.h>
#include <hip/hip_bf16.h>

typedef __attribute__((ext_vector_type(8))) short short8;
typedef __attribute__((ext_vector_type(4))) float f32x4;
typedef __attribute__((ext_vector_type(4))) int int4v;
typedef __attribute__((ext_vector_type(8))) char char8v;
typedef __attribute__((ext_vector_type(4), aligned(4))) unsigned int uint4a;

static constexpr int B = 64, N = 198, C = 768, H = 12, D = 64;
static constexpr int M = B * N;          // 12672 = 99*128
static constexpr int BH = B * H;         // 768
static constexpr int O3C = 3 * C;        // 2304 = 18*128
static constexpr int NXB = 99;           // M/128
static constexpr int TLD8 = 144;         // gemm1 epilogue i8 tile stride
static constexpr int AL8 = 272;          // attn P-stripe i8 stride
static constexpr int VNP = 256;          // V^T i8 padded cols

// ---- workspace layout (bytes) ----
static constexpr size_t OFF_MEANS = 0;
static constexpr size_t OFF_TAB   = 256;     // 129 + 16 doubles
static constexpr size_t OFF_PARTA = 2048;    // 2048 doubles
static constexpr size_t OFF_PARTP = 18432;   // 2048 doubles
static constexpr size_t OFF_XS    = 36864;
static constexpr size_t SZ_XS     = (size_t)M * C;           // sign(x) i8
static constexpr size_t OFF_WQS   = OFF_XS + SZ_XS;
static constexpr size_t SZ_WQS    = (size_t)O3C * C;
static constexpr size_t OFF_WPS   = OFF_WQS + SZ_WQS;
static constexpr size_t SZ_WPS    = (size_t)C * C;
static constexpr size_t OFF_Q     = OFF_WPS + SZ_WPS;
static constexpr size_t SZ_QK8    = (size_t)BH * N * D;      // i8
static constexpr size_t OFF_K     = OFF_Q + SZ_QK8;
static constexpr size_t OFF_VT    = OFF_K + SZ_QK8;
static constexpr size_t SZ_VT8    = (size_t)BH * D * VNP;    // i8
static constexpr size_t OFF_OS    = OFF_VT + SZ_VT8;         // i8 [M,C]

#define GLOAD_LDS16(g, l)                                                  \
  __builtin_amdgcn_global_load_lds(                                        \
      (const __attribute__((address_space(1))) void*)(g),                  \
      (__attribute__((address_space(3))) void*)(l), 16, 0, 0)

__global__ void finalize_kernel(const double* __restrict__ pA, const double* __restrict__ pP,
                                double* __restrict__ means, double* __restrict__ tab,
                                const float* cq, const float* ck) {
  __shared__ double sm[256];
  int t = threadIdx.x;
  double s = 0.0;
  for (int j = t; j < 2048; j += 256) s += pA[j];
  sm[t] = s;
  __syncthreads();
  for (int off = 128; off > 0; off >>= 1) { if (t < off) sm[t] += sm[t + off]; __syncthreads(); }
  if (t == 0) means[0] = sm[0] / (double)((size_t)O3C * C);
  __syncthreads();
  s = 0.0;
  for (int j = t; j < 2048; j += 256) s += pP[j];
  sm[t] = s;
  __syncthreads();
  for (int off = 128; off > 0; off >>= 1) { if (t < off) sm[t] += sm[t + off]; __syncthreads(); }
  if (t == 0) means[1] = sm[0] / (double)((size_t)C * C);
  double delta = (double)cq[0] * (double)ck[0] * 0.125;
  if (t < 129) tab[t] = exp((double)(t - 128) * delta);
  if (t < 16) tab[129 + t] = exp((double)t * delta);   // T2: exp(+j*delta)
}

// ---------- merged sign kernel, FUSED |w| partial sums ----------
__global__ void sign8_all_kernel(const float* __restrict__ x, signed char* __restrict__ Xs,
                                 const float* __restrict__ qw, signed char* __restrict__ Wq,
                                 const float* __restrict__ pw, signed char* __restrict__ Wp,
                                 int nx8, int nq8, int np8, const float* alpha,
                                 double* __restrict__ partA, double* __restrict__ partP) {
  __shared__ double sm[256];
  float a = alpha[0];
  signed char posx = (a > 0.0f) ? 1 : ((a < 0.0f) ? -1 : 0);
  int total = nx8 + nq8 + np8;
  int stride = 256 * gridDim.x;
  double sq = 0.0, sp = 0.0;
  for (int i = blockIdx.x * 256 + threadIdx.x; i < total; i += stride) {
    const float* src;
    signed char* dst;
    int j;
    signed char pos;
    int which;
    if (i < nx8) { src = x; dst = Xs; j = i; pos = posx; which = 0; }
    else if (i < nx8 + nq8) { src = qw; dst = Wq; j = i - nx8; pos = 1; which = 1; }
    else { src = pw; dst = Wp; j = i - nx8 - nq8; pos = 1; which = 2; }
    signed char neg = (signed char)(-pos);
    const float4* xp = (const float4*)(src + (size_t)j * 8);
    float4 u = xp[0], v = xp[1];
    float vals[8] = {u.x, u.y, u.z, u.w, v.x, v.y, v.z, v.w};
    char8v s;
    double asum = 0.0;
#pragma unroll
    for (int k = 0; k < 8; ++k) {
      s[k] = vals[k] > 0.0f ? pos : (vals[k] < 0.0f ? neg : (signed char)0);
      asum += (double)fabsf(vals[k]);
    }
    if (which == 1) sq += asum;
    else if (which == 2) sp += asum;
    *(char8v*)(dst + (size_t)j * 8) = s;
  }
  sm[threadIdx.x] = sq;
  __syncthreads();
  for (int off = 128; off > 0; off >>= 1) {
    if (threadIdx.x < (unsigned)off) sm[threadIdx.x] += sm[threadIdx.x + off];
    __syncthreads();
  }
  if (threadIdx.x == 0) partA[blockIdx.x] = sm[0];
  __syncthreads();
  sm[threadIdx.x] = sp;
  __syncthreads();
  for (int off = 128; off > 0; off >>= 1) {
    if (threadIdx.x < (unsigned)off) sm[threadIdx.x] += sm[threadIdx.x + off];
    __syncthreads();
  }
  if (threadIdx.x == 0) partP[blockIdx.x] = sm[0];
}

// XCD-affinity decode
static __device__ inline bool xcd_decode(int lin, int nyb, int& x, int& y) {
  int k = lin & 7;
  int q = lin >> 3;
  int xi = q / nyb;
  y = q - xi * nyb;
  x = xi * 8 + k;
  return x < NXB;
}

// ---------- staged i8 GEMM, BK=64, depth-2 prefetch (3 buffers, counted vmcnt) ----------
static __device__ inline void stage_i8(const signed char* __restrict__ A,
                                       const signed char* __restrict__ Bmat,
                                       int i0, int o0, int k0,
                                       char* AsB, char* BsB) {
  int tid = threadIdx.x;
  int lane = tid & 63, w = tid >> 6;
#pragma unroll
  for (int c = 0; c < 2; ++c) {
    int ccb = w * 64 + c * 256;          // wave-uniform 16B-chunk base
    int cc = ccb + lane;
    int row = cc >> 2, cwl = cc & 3;
    int sc16 = (cwl ^ ((row >> 1) & 3)) * 16;   // pre-swizzled source
    GLOAD_LDS16(&A[(size_t)(i0 + row) * C + k0 + sc16], AsB + (size_t)ccb * 16);
    GLOAD_LDS16(&Bmat[(size_t)(o0 + row) * C + k0 + sc16], BsB + (size_t)ccb * 16);
  }
}

static __device__ inline void compute_i8(const signed char (*As)[64],
                                         const signed char (*Bs)[64],
                                         int4v acc[4][4]) {
  int lane = threadIdx.x & 63, w = threadIdx.x >> 6, wr = w >> 1, wc = w & 1;
  int g = lane >> 4;                     // k-chunk 0..3
  int4v af[4], bf[4];
#pragma unroll
  for (int m = 0; m < 4; ++m) {
    int row = wr * 64 + m * 16 + (lane & 15);
    af[m] = *(const int4v*)&As[row][((g ^ ((row >> 1) & 3))) * 16];
  }
#pragma unroll
  for (int n2 = 0; n2 < 4; ++n2) {
    int row = wc * 64 + n2 * 16 + (lane & 15);
    bf[n2] = *(const int4v*)&Bs[row][((g ^ ((row >> 1) & 3))) * 16];
  }
  __builtin_amdgcn_s_setprio(1);
#pragma unroll
  for (int m = 0; m < 4; ++m)
#pragma unroll
    for (int n2 = 0; n2 < 4; ++n2)
      acc[m][n2] = __builtin_amdgcn_mfma_i32_16x16x64_i8(af[m], bf[n2], acc[m][n2], 0, 0, 0);
  __builtin_amdgcn_s_setprio(0);
}

// Depth-2 pipeline over 3 buffers (r16 structure, best measured).
static __device__ inline void gemm_dbuf_i8(const signed char* __restrict__ A,
                                           const signed char* __restrict__ Bmat,
                                           int i0, int o0, char* smem, int4v acc[4][4]) {
  stage_i8(A, Bmat, i0, o0, 0, smem, smem + 8192);
  stage_i8(A, Bmat, i0, o0, 64, smem + 16384, smem + 16384 + 8192);
  asm volatile("s_waitcnt vmcnt(4)" ::: "memory");
  __builtin_amdgcn_sched_barrier(0);
  __builtin_amdgcn_s_barrier();
#pragma unroll
  for (int t = 0; t < 12; ++t) {
    const int cu = t % 3;                 // compile-time under full unroll
    if (t < 10)
      stage_i8(A, Bmat, i0, o0, (t + 2) * 64,
               smem + ((t + 2) % 3) * 16384, smem + ((t + 2) % 3) * 16384 + 8192);
    compute_i8((const signed char(*)[64])(smem + cu * 16384),
               (const signed char(*)[64])(smem + cu * 16384 + 8192), acc);
    if (t < 10) {
      asm volatile("s_waitcnt vmcnt(4)" ::: "memory");
      __builtin_amdgcn_sched_barrier(0);
      __builtin_amdgcn_s_barrier();
    } else if (t == 10) {
      asm volatile("s_waitcnt vmcnt(0)" ::: "memory");
      __builtin_amdgcn_sched_barrier(0);
      __builtin_amdgcn_s_barrier();
    }
  }
}

// ---------- GEMM1: qkv = sign(x) @ sign(Wqkv)^T, i8 outputs ----------
__global__ __launch_bounds__(256) void gemm1_kernel(
    const signed char* __restrict__ Xs, const signed char* __restrict__ Wqs,
    const double* __restrict__ means,
    const float* cin, const float* cq, const float* ck,
    const float* cv1, const float* cv2, const float* cv3,
    const float* __restrict__ movq, const float* __restrict__ movk, const float* __restrict__ movv,
    signed char* __restrict__ Qs8, signed char* __restrict__ Ks8, signed char* __restrict__ Vt8) {
  int bx, by;
  if (!xcd_decode(blockIdx.x, O3C / 128, bx, by)) return;
  __shared__ __align__(16) char smem[49152];
  signed char* tile8 = (signed char*)smem;   // [128][TLD8] = 18432 B, aliases staging
  int4v acc[4][4] = {};
  int i0 = bx * 128, o0 = by * 128;
  gemm_dbuf_i8(Xs, Wqs, i0, o0, smem, acc);
  int tid = threadIdx.x;
  int lane = tid & 63, w = tid >> 6, wr = w >> 1, wc = w & 1;
  double cw_ = (double)cin[0] * means[0];
  float dq = cq[0], dk = ck[0];
  signed char sq8 = dq > 0.0f ? 1 : (dq < 0.0f ? -1 : 0);
  signed char sk8 = dk > 0.0f ? 1 : (dk < 0.0f ? -1 : 0);
  double aa1 = fabs((double)cv1[0]), aa2 = fabs((double)cv2[0]), aa3 = fabs((double)cv3[0]);
  int t = o0 / C;
  int rem0 = o0 - t * C;
  signed char sg8 = t == 0 ? sq8 : sk8;
  const float* mov = t == 0 ? movq : (t == 1 ? movk : movv);
  __syncthreads();                        // staging reads done before tile8 overwrite
#pragma unroll
  for (int m = 0; m < 4; ++m)
#pragma unroll
    for (int n2 = 0; n2 < 4; ++n2)
#pragma unroll
      for (int r = 0; r < 4; ++r) {
        int rowL = wr * 64 + m * 16 + (lane >> 4) * 4 + r;
        int colL = wc * 64 + n2 * 16 + (lane & 15);
        int rem = rem0 + colL;
        int h = rem >> 6, d = rem & 63;
        double g = (double)acc[m][n2][r] * cw_;
        if (t < 2) {
          double v = g + (double)mov[h * D + d];
          tile8[rowL * TLD8 + colL] = v > 0.0 ? sg8 : (v < 0.0 ? (signed char)(-sg8) : (signed char)0);
        } else {
          double rr = g + (double)mov[h * D + d];
          double b1 = rr > 0.0 ? aa1 : (rr < 0.0 ? -aa1 : 0.0);
          rr -= b1;
          double b2 = rr > 0.0 ? aa2 : (rr < 0.0 ? -aa2 : 0.0);
          rr -= b2;
          double b3 = rr > 0.0 ? aa3 : (rr < 0.0 ? -aa3 : 0.0);
          tile8[colL * TLD8 + rowL] = (signed char)(int)rint(4.0 * (b1 + b2 + b3)); // transposed
        }
      }
  __syncthreads();
  if (t < 2) {
    signed char* dst = t == 0 ? Qs8 : Ks8;
#pragma unroll
    for (int it = 0; it < 4; ++it) {
      int c = tid + it * 256;            // 1024 chunks of 16B
      int rowL = c >> 3, cch = c & 7;
      int gr = i0 + rowL;
      int b = gr / N, nn = gr - b * N;
      int rem = rem0 + cch * 16;
      int h = rem >> 6, d = rem & 63;
      *(uint4a*)&dst[((size_t)(b * H + h) * N + nn) * 64 + d] =
          *(const uint4a*)&tile8[rowL * TLD8 + cch * 16];
    }
  } else {
#pragma unroll
    for (int it = 0; it < 4; ++it) {
      int c = tid + it * 256;
      int colL = c >> 3, tch = c & 7;
      int rem = rem0 + colL;
      int h = rem >> 6, d = rem & 63;
      int gr0 = i0 + tch * 16;
      int b0 = gr0 / N, nn0 = gr0 - b0 * N;
      if (nn0 + 16 <= N) {
        *(uint4a*)&Vt8[((size_t)(b0 * H + h) * 64 + d) * VNP + nn0] =
            *(const uint4a*)&tile8[colL * TLD8 + tch * 16];
      } else {
#pragma unroll
        for (int j = 0; j < 16; ++j) {
          int gr = gr0 + j;
          int b = gr / N, nn = gr - b * N;
          Vt8[((size_t)(b * H + h) * 64 + d) * VNP + nn] = tile8[colL * TLD8 + tch * 16 + j];
        }
      }
    }
  }
}

// ---------- fused attention v6: all-i8, 4 waves/block, XCD-affine ----------
__global__ __launch_bounds__(256) void attn_kernel(
    const signed char* __restrict__ Qs8, const signed char* __restrict__ Ks8,
    const signed char* __restrict__ Vt8, const double* __restrict__ tab,
    const float* __restrict__ movatt,
    const float* ca1p, const float* ca2p, const float* ca3p, const float* cipp,
    signed char* __restrict__ Os) {
  __shared__ double Tl1[9];    // exp((16i-128)*delta)
  __shared__ double Tl2[16];   // exp(j*delta)
  __shared__ signed char Al8[4][16 * AL8];
  int i = blockIdx.x;
  int xcd = i & 7;
  int q = i >> 3;
  int rt = q % 13;
  int grp = q / 13;
  int tid = threadIdx.x;
  int w = tid >> 6, lane = tid & 63;
  int bh = (grp * 4 + w) * 8 + xcd;
  int b = bh / H, h = bh - b * H;
  int g = lane >> 4, q16 = lane & 15;
  if (tid < 9) Tl1[tid] = tab[16 * tid];
  if (tid >= 32 && tid < 48) Tl2[tid - 32] = tab[129 + (tid - 32)];
  for (int ii = lane; ii < 192; ii += 64) {
    int row = ii / 12, cd = ii - row * 12;
    *(int*)&Al8[w][row * AL8 + 208 + cd * 4] = 0;
  }
  __syncthreads();
  double ca1 = (double)ca1p[0], ca2 = (double)ca2p[0], ca3 = (double)ca3p[0];
  double t1 = 0.5 * ca1, t2 = 0.5 * ca2, t3 = 0.5 * ca3;
  int q1 = (int)rint(4.0 * ca1), q2 = (int)rint(4.0 * ca2), q3 = (int)rint(4.0 * ca3);
  float cip = cipp[0];
  signed char cp = cip > 0.0f ? 1 : (cip < 0.0f ? -1 : 0);

  int4v qf = {};
  int qrow = rt * 16 + q16;
  if (qrow < N) qf = *(const int4v*)&Qs8[((size_t)bh * N + qrow) * 64 + g * 16];
  int4v sacc[13] = {};
#pragma unroll
  for (int ct = 0; ct < 13; ++ct) {
    int krow = ct * 16 + q16;
    int4v kf = {};
    if (krow < N) kf = *(const int4v*)&Ks8[((size_t)bh * N + krow) * 64 + g * 16];
    sacc[ct] = __builtin_amdgcn_mfma_i32_16x16x64_i8(qf, kf, sacc[ct], 0, 0, 0);
  }
#pragma unroll
  for (int r = 0; r < 4; ++r) {
    int rowg = rt * 16 + g * 4 + r;
    int rowc = rowg < N ? rowg : N - 1;
    const float* mrow = movatt + ((size_t)h * N + rowc) * N;
    int mx = -1000000;
#pragma unroll
    for (int ct = 0; ct < 13; ++ct) {
      int colc = ct * 16 + q16;
      if (colc < N) mx = max(mx, sacc[ct][r]);
    }
    mx = max(mx, __shfl_xor(mx, 1));
    mx = max(mx, __shfl_xor(mx, 2));
    mx = max(mx, __shfl_xor(mx, 4));
    mx = max(mx, __shfl_xor(mx, 8));
    double ev[13];
    double ssum = 0.0;
#pragma unroll
    for (int ct = 0; ct < 13; ++ct) {
      int colc = ct * 16 + q16;
      int idx = sacc[ct][r] - mx + 128;
      idx = idx > 128 ? 128 : idx;
      double e = (colc < N) ? Tl1[idx >> 4] * Tl2[idx & 15] : 0.0;
      ev[ct] = e;
      ssum += e;
    }
    ssum += __shfl_xor(ssum, 1);
    ssum += __shfl_xor(ssum, 2);
    ssum += __shfl_xor(ssum, 4);
    ssum += __shfl_xor(ssum, 8);
    double rec = 1.0 / ssum;
#pragma unroll
    for (int ct = 0; ct < 13; ++ct) {
      int colc = ct * 16 + q16;
      int colb = colc < N ? colc : N - 1;
      double at = ev[ct] * rec + (double)mrow[colb];
      int p4 = 0;
      double rr = at;
      if (rr > t1) { p4 += q1; rr -= ca1; }
      if (rr > t2) { p4 += q2; rr -= ca2; }
      if (rr > t3) { p4 += q3; }
      Al8[w][(g * 4 + r) * AL8 + colc] = (signed char)((colc < N) ? p4 : 0);
    }
  }
  int4v oacc[4] = {};
#pragma unroll
  for (int kt = 0; kt < 4; ++kt) {
    int4v af = *(const int4v*)&Al8[w][q16 * AL8 + kt * 64 + g * 16];
#pragma unroll
    for (int dt = 0; dt < 4; ++dt) {
      int4v bv = *(const int4v*)&Vt8[((size_t)bh * 64 + dt * 16 + q16) * VNP + kt * 64 + g * 16];
      oacc[dt] = __builtin_amdgcn_mfma_i32_16x16x64_i8(af, bv, oacc[dt], 0, 0, 0);
    }
  }
#pragma unroll
  for (int dt = 0; dt < 4; ++dt)
#pragma unroll
    for (int r = 0; r < 4; ++r) {
      int rowg = rt * 16 + g * 4 + r;
      if (rowg < N) {
        int d = dt * 16 + q16;
        int s = oacc[dt][r];
        Os[((size_t)(b * N + rowg)) * C + h * D + d] =
            s > 0 ? cp : (s < 0 ? (signed char)(-cp) : (signed char)0);
      }
    }
}

// ---------- GEMM2 ----------
__global__ __launch_bounds__(256) void gemm2_kernel(
    const signed char* __restrict__ Os, const signed char* __restrict__ Wps,
    const double* __restrict__ means, const float* cip, const float* __restrict__ proj_b,
    float* __restrict__ out) {
  int bx, by;
  if (!xcd_decode(blockIdx.x, C / 128, bx, by)) return;
  __shared__ __align__(16) char smem[49152];
  int4v acc[4][4] = {};
  int i0 = bx * 128, o0 = by * 128;
  gemm_dbuf_i8(Os, Wps, i0, o0, smem, acc);
  int lane = threadIdx.x & 63, w = threadIdx.x >> 6, wr = w >> 1, wc = w & 1;
  double cw_ = (double)cip[0] * means[1];
#pragma unroll
  for (int m = 0; m < 4; ++m)
#pragma unroll
    for (int n2 = 0; n2 < 4; ++n2)
#pragma unroll
      for (int r = 0; r < 4; ++r) {
        int row = i0 + wr * 64 + m * 16 + (lane >> 4) * 4 + r;
        int col = o0 + wc * 64 + n2 * 16 + (lane & 15);
        double v = (double)acc[m][n2][r] * cw_ + (double)proj_b[col];
        out[(size_t)row * C + col] = (float)v;
      }
}

extern "C" void kernel_launch(void* const* d_in, const int* in_sizes, int n_in,
                              void* d_out, int out_size, void* d_ws, size_t ws_size,
                              hipStream_t stream) {
  const float* x      = (const float*)d_in[0];
  const float* qkv_w  = (const float*)d_in[1];
  const float* proj_w = (const float*)d_in[2];
  const float* proj_b = (const float*)d_in[3];
  const float* movq   = (const float*)d_in[4];
  const float* movk   = (const float*)d_in[5];
  const float* movv   = (const float*)d_in[6];
  const float* movatt = (const float*)d_in[7];
  const float* c_inq  = (const float*)d_in[8];
  const float* c_q    = (const float*)d_in[9];
  const float* c_k    = (const float*)d_in[10];
  const float* c_v1   = (const float*)d_in[11];
  const float* c_v2   = (const float*)d_in[12];
  const float* c_v3   = (const float*)d_in[13];
  const float* c_a1   = (const float*)d_in[14];
  const float* c_a2   = (const float*)d_in[15];
  const float* c_a3   = (const float*)d_in[16];
  const float* c_inp  = (const float*)d_in[17];

  char* ws = (char*)d_ws;
  double* means = (double*)(ws + OFF_MEANS);
  double* tab   = (double*)(ws + OFF_TAB);
  double* partA = (double*)(ws + OFF_PARTA);
  double* partP = (double*)(ws + OFF_PARTP);
  signed char* Xs  = (signed char*)(ws + OFF_XS);
  signed char* Wqs = (signed char*)(ws + OFF_WQS);
  signed char* Wps = (signed char*)(ws + OFF_WPS);
  signed char* Qs8 = (signed char*)(ws + OFF_Q);
  signed char* Ks8 = (signed char*)(ws + OFF_K);
  signed char* Vt8 = (signed char*)(ws + OFF_VT);
  signed char* Os  = (signed char*)(ws + OFF_OS);

  sign8_all_kernel<<<2048, 256, 0, stream>>>(x, Xs, qkv_w, Wqs, proj_w, Wps,
                                             M * C / 8, O3C * C / 8, C * C / 8, c_inq,
                                             partA, partP);
  finalize_kernel<<<1, 256, 0, stream>>>(partA, partP, means, tab, c_q, c_k);
  gemm1_kernel<<<104 * (O3C / 128), 256, 0, stream>>>(
      Xs, Wqs, means, c_inq, c_q, c_k, c_v1, c_v2, c_v3, movq, movk, movv, Qs8, Ks8, Vt8);
  attn_kernel<<<8 * 13 * (BH / 32), 256, 0, stream>>>(Qs8, Ks8, Vt8, tab, movatt, c_a1, c_a2, c_a3, c_inp, Os);
  gemm2_kernel<<<104 * (C / 128), 256, 0, stream>>>(
      Os, Wps, means, c_inp, proj_b, (float*)d_out);
}